// Round 1
// baseline (3362.978 us; speedup 1.0000x reference)
//
#include <hip/hip_runtime.h>

#define HDIM 256
#define TLEN 2048
#define SELEN 64
#define MSZ 8

typedef _Float16 f16x2 __attribute__((ext_vector_type(2)));

__device__ __forceinline__ float dot2f(unsigned int w, unsigned int h, float acc) {
  return __builtin_amdgcn_fdot2(__builtin_bit_cast(f16x2, w),
                                __builtin_bit_cast(f16x2, h), acc, false);
}

__device__ __forceinline__ unsigned int pack2(float a, float b) {
  f16x2 v;
  v.x = (_Float16)a; v.y = (_Float16)b;
  return __builtin_bit_cast(unsigned int, v);
}

__device__ __forceinline__ float sigm(float x)  { return 1.0f / (1.0f + __expf(-x)); }
__device__ __forceinline__ float tanh_f(float x) { return 1.0f - 2.0f / (__expf(2.0f * x) + 1.0f); }

// LDS layout (bytes)
#define WO_OFF    0        // 512 thr * 64 dwords  = 131072 B  (o-gate fp16x2 weights)
#define PART_OFF  131072   // 512 * float4         = 8192 B    (partial sums)
#define WIH_OFF   139264   // 1024 rows * float4   = 16384 B   (input-proj weights, padded)
#define CNT_OFF   155648   // 2048 * u8            = 2048 B    (window cover counts)
#define H2_OFF    157696   // 128 dwords           = 512 B     (h as packed fp16 pairs)
#define LDS_BYTES 158208

extern __shared__ unsigned char smem[];

__global__ __launch_bounds__(512, 2)
void lstm_seq_kernel(const float* __restrict__ touch, const float* __restrict__ gaze,
                     const float* __restrict__ l,
                     const float* __restrict__ tWih, const float* __restrict__ tWhh,
                     const float* __restrict__ tbih, const float* __restrict__ tbhh,
                     const float* __restrict__ gWih, const float* __restrict__ gWhh,
                     const float* __restrict__ gbih, const float* __restrict__ gbhh,
                     float* __restrict__ ws)
{
  const int bid  = (int)blockIdx.x;   // 0..63
  const int lsel = bid >> 5;          // 0 = touch, 1 = gaze
  const int b    = bid & 31;
  const int tid  = (int)threadIdx.x;  // 0..511
  const int kh   = tid >> 8;          // k-half: k in [128*kh, 128*kh+128)

  const float* __restrict__ x   = lsel ? gaze : touch;
  const float* __restrict__ Wih = lsel ? gWih : tWih;
  const float* __restrict__ Whh = lsel ? gWhh : tWhh;
  const float* __restrict__ bih = lsel ? gbih : tbih;
  const float* __restrict__ bhh = lsel ? gbhh : tbhh;
  const int D = lsel ? 4 : 3;

  unsigned int*  woL  = (unsigned int*)(smem + WO_OFF);
  float4*        part = (float4*)(smem + PART_OFF);
  float4*        wihF = (float4*)(smem + WIH_OFF);
  unsigned char* cntL = smem + CNT_OFF;
  unsigned int*  h2   = (unsigned int*)(smem + H2_OFF);

  // ---- load recurrent weights: rows n(i), n+256(f), n+512(g) -> 192 VGPRs; row n+768(o) -> LDS
  unsigned int wi[64], wf[64], wg[64];
  {
    const float2* ri = (const float2*)(Whh + (size_t)(tid & 255) * HDIM + kh * 128);
    const float2* rf = (const float2*)((const float*)ri + 256 * HDIM);
    const float2* rg = (const float2*)((const float*)ri + 512 * HDIM);
    const float2* ro = (const float2*)((const float*)ri + 768 * HDIM);
    #pragma unroll
    for (int d = 0; d < 64; ++d) {
      float2 a = ri[d], bb = rf[d], c = rg[d], e = ro[d];
      wi[d] = pack2(a.x, a.y);
      wf[d] = pack2(bb.x, bb.y);
      wg[d] = pack2(c.x, c.y);
      woL[(((d >> 2) * 512 + tid) << 2) | (d & 3)] = pack2(e.x, e.y);
    }
  }

  // ---- input-projection weights, fp32, padded to 4 cols
  for (int r = tid; r < 1024; r += 512) {
    const float* wr = Wih + (size_t)r * D;
    float4 v;
    v.x = wr[0]; v.y = wr[1]; v.z = wr[2];
    v.w = (D == 4) ? wr[3] : 0.0f;
    wihF[r] = v;
  }

  // ---- glimpse-window cover counts cnt[t]
  int sreg[MSZ];
  #pragma unroll
  for (int m = 0; m < MSZ; ++m) sreg[m] = (int)(l[b * MSZ + m] * 2048.0f);
  for (int t0 = tid; t0 < TLEN; t0 += 512) {
    int c = 0;
    #pragma unroll
    for (int m = 0; m < MSZ; ++m) c += (t0 >= sreg[m] && t0 < sreg[m] + SELEN) ? 1 : 0;
    cntL[t0] = (unsigned char)c;
  }

  if (tid < 128) h2[tid] = 0u;   // h_0 = 0

  float bi_ = 0.f, bf_ = 0.f, bg_ = 0.f, bo_ = 0.f;
  float x0 = 0.f, x1 = 0.f, x2 = 0.f, x3 = 0.f;
  float cst = 0.f, Sall = 0.f, Swin = 0.f;
  const float* xbase = x + (size_t)b * TLEN * D;
  if (tid < 256) {
    bi_ = bih[tid]       + bhh[tid];
    bf_ = bih[tid + 256] + bhh[tid + 256];
    bg_ = bih[tid + 512] + bhh[tid + 512];
    bo_ = bih[tid + 768] + bhh[tid + 768];
    x0 = xbase[0]; x1 = xbase[1]; x2 = xbase[2];
    x3 = (D == 4) ? xbase[3] : 0.0f;
  }
  __syncthreads();

  const uint4* h2v = (const uint4*)h2;
  const uint4* wov = (const uint4*)woL;

  for (int t = 0; t < TLEN; ++t) {
    // stage 1: all 512 threads, each: 4 gate rows x its 128-k half
    float ai = 0.f, af = 0.f, ag = 0.f, ao = 0.f;
    #pragma unroll
    for (int kk = 0; kk < 16; ++kk) {
      const uint4 hh  = h2v[(kh << 4) + kk];       // wave-uniform -> broadcast
      const uint4 wo4 = wov[(kk << 9) + tid];      // 16 B/lane contiguous -> conflict-free
      ai = dot2f(wi[4*kk+0], hh.x, ai);
      af = dot2f(wf[4*kk+0], hh.x, af);
      ag = dot2f(wg[4*kk+0], hh.x, ag);
      ao = dot2f(wo4.x,      hh.x, ao);
      ai = dot2f(wi[4*kk+1], hh.y, ai);
      af = dot2f(wf[4*kk+1], hh.y, af);
      ag = dot2f(wg[4*kk+1], hh.y, ag);
      ao = dot2f(wo4.y,      hh.y, ao);
      ai = dot2f(wi[4*kk+2], hh.z, ai);
      af = dot2f(wf[4*kk+2], hh.z, af);
      ag = dot2f(wg[4*kk+2], hh.z, ag);
      ao = dot2f(wo4.z,      hh.z, ao);
      ai = dot2f(wi[4*kk+3], hh.w, ai);
      af = dot2f(wf[4*kk+3], hh.w, af);
      ag = dot2f(wg[4*kk+3], hh.w, ag);
      ao = dot2f(wo4.w,      hh.w, ao);
    }
    part[tid] = make_float4(ai, af, ag, ao);
    __syncthreads();

    // stage 2: threads 0..255 (unit n = tid) reduce, gate, update state
    if (tid < 256) {
      const float4 p0  = part[tid];
      const float4 p1  = part[tid + 256];
      const float4 wi0 = wihF[tid];
      const float4 wi1 = wihF[tid + 256];
      const float4 wi2 = wihF[tid + 512];
      const float4 wi3 = wihF[tid + 768];
      float gi = p0.x + p1.x + bi_ + x0*wi0.x + x1*wi0.y + x2*wi0.z + x3*wi0.w;
      float gf = p0.y + p1.y + bf_ + x0*wi1.x + x1*wi1.y + x2*wi1.z + x3*wi1.w;
      float gg = p0.z + p1.z + bg_ + x0*wi2.x + x1*wi2.y + x2*wi2.z + x3*wi2.w;
      float go = p0.w + p1.w + bo_ + x0*wi3.x + x1*wi3.y + x2*wi3.z + x3*wi3.w;
      const float si = sigm(gi), sf = sigm(gf), so = sigm(go);
      const float tg = tanh_f(gg);
      cst = sf * cst + si * tg;
      const float hv = so * tanh_f(cst);
      const float rh = fmaxf(hv, 0.0f);
      Sall += rh;
      Swin += (float)cntL[t] * rh;
      ((_Float16*)h2)[tid] = (_Float16)hv;
      if (t + 1 < TLEN) {   // prefetch x for next step
        const float* xp = xbase + (size_t)(t + 1) * D;
        x0 = xp[0]; x1 = xp[1]; x2 = xp[2];
        x3 = (D == 4) ? xp[3] : 0.0f;
      }
    }
    __syncthreads();
  }

  if (tid < 256) {
    ws[((0 * 2 + lsel) * 32 + b) * HDIM + tid] = Sall;
    ws[((1 * 2 + lsel) * 32 + b) * HDIM + tid] = Swin;
  }
}

__global__ void proj_kernel(const float* __restrict__ ws,
                            const float* __restrict__ tlw, const float* __restrict__ tlb,
                            const float* __restrict__ glw, const float* __restrict__ glb,
                            float* __restrict__ out)
{
  const int b    = (int)blockIdx.x >> 2;
  const int seg  = (int)blockIdx.x & 3;   // 0 t_mean, 1 t_attn, 2 g_mean, 3 g_attn
  const int j    = (int)threadIdx.x;
  const int lsel = seg >> 1;
  const int kind = seg & 1;
  const float* __restrict__ W    = lsel ? glw : tlw;
  const float* __restrict__ bias = lsel ? glb : tlb;
  const float scale = kind ? (1.0f / 512.0f) : (1.0f / 2048.0f);

  __shared__ float Sv[HDIM];
  Sv[j] = ws[((kind * 2 + lsel) * 32 + b) * HDIM + j] * scale;
  __syncthreads();

  float acc = bias[j];
  const float4* wr4 = (const float4*)(W + (size_t)j * HDIM);
  #pragma unroll 8
  for (int k4 = 0; k4 < HDIM / 4; ++k4) {
    const float4 w = wr4[k4];
    acc = fmaf(Sv[4*k4],     w.x, acc);
    acc = fmaf(Sv[4*k4 + 1], w.y, acc);
    acc = fmaf(Sv[4*k4 + 2], w.z, acc);
    acc = fmaf(Sv[4*k4 + 3], w.w, acc);
  }
  out[(size_t)b * 1024 + seg * HDIM + j] = acc;
}

extern "C" void kernel_launch(void* const* d_in, const int* in_sizes, int n_in,
                              void* d_out, int out_size, void* d_ws, size_t ws_size,
                              hipStream_t stream) {
  (void)in_sizes; (void)n_in; (void)out_size; (void)ws_size;
  const float* touch = (const float*)d_in[0];
  const float* gaze  = (const float*)d_in[1];
  const float* l     = (const float*)d_in[2];
  const float* tWih  = (const float*)d_in[3];
  const float* tWhh  = (const float*)d_in[4];
  const float* tbih  = (const float*)d_in[5];
  const float* tbhh  = (const float*)d_in[6];
  const float* gWih  = (const float*)d_in[7];
  const float* gWhh  = (const float*)d_in[8];
  const float* gbih  = (const float*)d_in[9];
  const float* gbhh  = (const float*)d_in[10];
  const float* tlw   = (const float*)d_in[11];
  const float* tlb   = (const float*)d_in[12];
  const float* glw   = (const float*)d_in[13];
  const float* glb   = (const float*)d_in[14];
  float* out = (float*)d_out;
  float* ws  = (float*)d_ws;

  hipFuncSetAttribute(reinterpret_cast<const void*>(&lstm_seq_kernel),
                      hipFuncAttributeMaxDynamicSharedMemorySize, LDS_BYTES);

  hipLaunchKernelGGL(lstm_seq_kernel, dim3(64), dim3(512), LDS_BYTES, stream,
                     touch, gaze, l, tWih, tWhh, tbih, tbhh,
                     gWih, gWhh, gbih, gbhh, ws);
  hipLaunchKernelGGL(proj_kernel, dim3(128), dim3(256), 0, stream,
                     ws, tlw, tlb, glw, glb, out);
}